// Round 1
// baseline (121.877 us; speedup 1.0000x reference)
//
#include <hip/hip_runtime.h>
#include <math.h>

namespace {

constexpr int B   = 2048;
constexpr int L   = 200;
constexpr int E   = 96;    // 3 * D_FEAT
constexpr int U   = 64;
constexpr int NA  = 36;    // HID_ATT
constexpr int H1  = 200;
constexpr int H2  = 80;

__device__ __forceinline__ float sigf(float x) {
    return 1.0f / (1.0f + __expf(-x));
}

// K0: collapse the linear attention MLP: v[j] = sum_k w_att2[k] * w_att1[k, j]
// vbuf[0..95]   = v1 + v3   (multiplies q; folded into per-row const)
// vbuf[96..191] = v2 - v3   (multiplies ub)
// vbuf[192..287]= v4        (multiplies q*ub)
// vbuf[288]     = w_att2·b_att1 + b_att2
__global__ void k_pre(const float* __restrict__ w_att1,
                      const float* __restrict__ b_att1,
                      const float* __restrict__ w_att2,
                      const float* __restrict__ b_att2,
                      float* __restrict__ vbuf) {
    __shared__ float v[4 * E];
    int t = threadIdx.x;               // 384 threads
    float s = 0.f;
    #pragma unroll
    for (int k = 0; k < NA; ++k) s += w_att2[k] * w_att1[k * 4 * E + t];
    v[t] = s;
    __syncthreads();
    if (t < E) {
        vbuf[t]         = v[t] + v[2 * E + t];
        vbuf[E + t]     = v[E + t] - v[2 * E + t];
        vbuf[2 * E + t] = v[3 * E + t];
    } else if (t == E) {
        float c = b_att2[0];
        for (int k = 0; k < NA; ++k) c += w_att2[k] * b_att1[k];
        vbuf[3 * E] = c;
    }
}

// K1: per-batch-row attention + browse + feat, then y1 = feat @ w1^T + b1
__global__ __launch_bounds__(256) void k_attn(
    const int* __restrict__ user, const int* __restrict__ item,
    const int* __restrict__ rec,
    const float* __restrict__ tu, const float* __restrict__ t1,
    const float* __restrict__ t2, const float* __restrict__ t3,
    const float* __restrict__ vbuf,
    const float* __restrict__ w1, const float* __restrict__ b1,
    float* __restrict__ y1)
{
    int b = blockIdx.x, t = threadIdx.x;
    __shared__ __align__(16) float s_w[E];
    __shared__ __align__(16) float s_feat[256];
    __shared__ float s_score[L];
    __shared__ int   s_idx[3 * L];
    __shared__ float s_cb;

    // q (=item_emb) into feat[0..95]; per-row weight w[e] = vu[e] + q[e]*v4[e]
    if (t < E) {
        int f = t >> 5, e = t & 31;
        const float* tab = (f == 0) ? t1 : ((f == 1) ? t2 : t3);
        float qv = tab[item[b * 3 + f] * 32 + e];
        s_feat[t]  = qv;
        s_w[t]     = vbuf[E + t] + qv * vbuf[2 * E + t];
        s_score[t] = qv * vbuf[t];           // temp for cb reduction
    }
    if (t >= 192) {                          // user_emb into feat[192..255]
        s_feat[t] = tu[user[b] * U + (t - 192)];
    }
    for (int i = t; i < 3 * L; i += 256) s_idx[i] = rec[b * 3 * L + i];
    __syncthreads();

    if (t == 0) {
        float c = vbuf[3 * E];
        for (int k = 0; k < E; ++k) c += s_score[k];
        s_cb = c;
    }
    __syncthreads();

    // phase A: one thread per history position -> score
    if (t < L) {
        int i0 = s_idx[t * 3], i1 = s_idx[t * 3 + 1], i2 = s_idx[t * 3 + 2];
        const float4* r0 = (const float4*)(t1 + i0 * 32);
        const float4* r1 = (const float4*)(t2 + i1 * 32);
        const float4* r2 = (const float4*)(t3 + i2 * 32);
        const float4* wv = (const float4*)s_w;
        float sc = s_cb;
        #pragma unroll
        for (int k = 0; k < 8; ++k) {
            float4 a = r0[k], w = wv[k];
            sc += a.x * w.x + a.y * w.y + a.z * w.z + a.w * w.w;
        }
        #pragma unroll
        for (int k = 0; k < 8; ++k) {
            float4 a = r1[k], w = wv[8 + k];
            sc += a.x * w.x + a.y * w.y + a.z * w.z + a.w * w.w;
        }
        #pragma unroll
        for (int k = 0; k < 8; ++k) {
            float4 a = r2[k], w = wv[16 + k];
            sc += a.x * w.x + a.y * w.y + a.z * w.z + a.w * w.w;
        }
        s_score[t] = (i0 == 0) ? 0.f : sc;   // mask
    }
    __syncthreads();

    // phase B: browse[e] = sum_l score[l] * ub[l, e]
    if (t < E) {
        int f = t >> 5, e = t & 31;
        const float* tab = (f == 0) ? t1 : ((f == 1) ? t2 : t3);
        float acc = 0.f;
        #pragma unroll 4
        for (int l = 0; l < L; ++l)
            acc += s_score[l] * tab[s_idx[l * 3 + f] * 32 + e];
        s_feat[E + t] = acc;
    }
    __syncthreads();

    // y1 = feat @ w1^T + b1  (one thread per output col)
    if (t < H1) {
        const float4* wr = (const float4*)(w1 + t * 256);
        const float4* fv = (const float4*)s_feat;
        float acc = b1[t];
        #pragma unroll
        for (int k = 0; k < 64; ++k) {
            float4 w = wr[k], f = fv[k];
            acc += w.x * f.x + w.y * f.y + w.z * f.z + w.w * f.w;
        }
        y1[b * H1 + t] = acc;
    }
}

// K2/K4: per-column batch stats; fold dice's normalization into scale/shift:
// xn = y*sc + sh  with sc = g/sqrt(var+eps), sh = be - mean*sc
template <int NCOL>
__global__ __launch_bounds__(256) void k_stats(
    const float* __restrict__ y, const float* __restrict__ g,
    const float* __restrict__ be, float* __restrict__ sc,
    float* __restrict__ sh)
{
    int j = blockIdx.x, t = threadIdx.x;
    float s = 0.f, s2 = 0.f;
    for (int b = t; b < B; b += 256) {
        float v = y[b * NCOL + j];
        s += v; s2 += v * v;
    }
    __shared__ float rs[256], rq[256];
    rs[t] = s; rq[t] = s2;
    __syncthreads();
    for (int o = 128; o > 0; o >>= 1) {
        if (t < o) { rs[t] += rs[t + o]; rq[t] += rq[t + o]; }
        __syncthreads();
    }
    if (t == 0) {
        float mean = rs[0] / (float)B;
        float var  = (rq[0] - (float)B * mean * mean) / (float)(B - 1);
        var = fmaxf(var, 0.f);
        float a = g[j] * rsqrtf(var + 1e-8f);
        sc[j] = a;
        sh[j] = be[j] - mean * a;
    }
}

// K3: dice(y1) then y2 = x @ w2^T + b2
__global__ __launch_bounds__(256) void k_mlp1(
    const float* __restrict__ y1, const float* __restrict__ sc1,
    const float* __restrict__ sh1, const float* __restrict__ al1,
    const float* __restrict__ w2, const float* __restrict__ b2,
    float* __restrict__ y2)
{
    int b = blockIdx.x, t = threadIdx.x;
    __shared__ __align__(16) float s_x[H1];
    if (t < H1) {
        float xn = y1[b * H1 + t] * sc1[t] + sh1[t];
        float p  = sigf(xn);
        s_x[t] = xn * (p + al1[t] * (1.f - p));
    }
    __syncthreads();
    if (t < H2) {
        const float4* wr = (const float4*)(w2 + t * H1);
        const float4* xv = (const float4*)s_x;
        float acc = b2[t];
        #pragma unroll
        for (int k = 0; k < H1 / 4; ++k) {
            float4 w = wr[k], x = xv[k];
            acc += w.x * x.x + w.y * x.y + w.z * x.z + w.w * x.w;
        }
        y2[b * H2 + t] = acc;
    }
}

// K5: dice(y2), final dot with w3, sigmoid
__global__ __launch_bounds__(128) void k_final(
    const float* __restrict__ y2, const float* __restrict__ sc2,
    const float* __restrict__ sh2, const float* __restrict__ al2,
    const float* __restrict__ w3, const float* __restrict__ b3,
    float* __restrict__ out)
{
    int b = blockIdx.x, t = threadIdx.x;
    __shared__ float s[H2];
    if (t < H2) {
        float xn = y2[b * H2 + t] * sc2[t] + sh2[t];
        float p  = sigf(xn);
        s[t] = xn * (p + al2[t] * (1.f - p)) * w3[t];
    }
    __syncthreads();
    if (t == 0) {
        float acc = b3[0];
        for (int k = 0; k < H2; ++k) acc += s[k];
        out[b] = sigf(acc);
    }
}

} // namespace

extern "C" void kernel_launch(void* const* d_in, const int* in_sizes, int n_in,
                              void* d_out, int out_size, void* d_ws, size_t ws_size,
                              hipStream_t stream) {
    const int*   user   = (const int*)d_in[0];
    const int*   item   = (const int*)d_in[1];
    const int*   rec    = (const int*)d_in[2];
    const float* tu     = (const float*)d_in[3];
    const float* t1     = (const float*)d_in[4];
    const float* t2     = (const float*)d_in[5];
    const float* t3     = (const float*)d_in[6];
    const float* w_att1 = (const float*)d_in[7];
    const float* b_att1 = (const float*)d_in[8];
    const float* w_att2 = (const float*)d_in[9];
    const float* b_att2 = (const float*)d_in[10];
    const float* w1     = (const float*)d_in[11];
    const float* b1     = (const float*)d_in[12];
    const float* a1     = (const float*)d_in[13];
    const float* g1     = (const float*)d_in[14];
    const float* be1    = (const float*)d_in[15];
    const float* w2     = (const float*)d_in[16];
    const float* b2     = (const float*)d_in[17];
    const float* a2     = (const float*)d_in[18];
    const float* g2     = (const float*)d_in[19];
    const float* be2    = (const float*)d_in[20];
    const float* w3     = (const float*)d_in[21];
    const float* b3     = (const float*)d_in[22];
    float* out = (float*)d_out;

    float* ws   = (float*)d_ws;
    float* vbuf = ws;                 // 289 used, pad to 320
    float* y1   = ws + 320;           // B*H1 = 409600
    float* sc1  = y1 + B * H1;        // 200
    float* sh1  = sc1 + H1;           // 200
    float* y2   = sh1 + H1;           // B*H2 = 163840
    float* sc2  = y2 + B * H2;        // 80
    float* sh2  = sc2 + H2;           // 80

    hipLaunchKernelGGL(k_pre,  dim3(1),  dim3(4 * E), 0, stream,
                       w_att1, b_att1, w_att2, b_att2, vbuf);
    hipLaunchKernelGGL(k_attn, dim3(B),  dim3(256), 0, stream,
                       user, item, rec, tu, t1, t2, t3, vbuf, w1, b1, y1);
    hipLaunchKernelGGL(k_stats<H1>, dim3(H1), dim3(256), 0, stream,
                       y1, g1, be1, sc1, sh1);
    hipLaunchKernelGGL(k_mlp1, dim3(B),  dim3(256), 0, stream,
                       y1, sc1, sh1, a1, w2, b2, y2);
    hipLaunchKernelGGL(k_stats<H2>, dim3(H2), dim3(256), 0, stream,
                       y2, g2, be2, sc2, sh2);
    hipLaunchKernelGGL(k_final, dim3(B), dim3(128), 0, stream,
                       y2, sc2, sh2, a2, w3, b3, out);
}

// Round 2
// 94.733 us; speedup vs baseline: 1.2865x; 1.2865x over previous
//
#include <hip/hip_runtime.h>
#include <math.h>

namespace {

constexpr int B   = 2048;
constexpr int L   = 200;
constexpr int E   = 96;    // 3 * D_FEAT
constexpr int U   = 64;
constexpr int NA  = 36;    // HID_ATT
constexpr int H1  = 200;
constexpr int H2  = 80;
constexpr int BPB = 4;     // batch rows per block, K1
constexpr int MB  = 2;     // batch rows per block, K2
constexpr int NB  = 64;    // batch rows per block, K3

__device__ __forceinline__ float sigf(float x) {
    return 1.0f / (1.0f + __expf(-x));
}

// ---------------------------------------------------------------------------
// K1: folded-attention scores + browse + feat + y1 = feat @ w1^T + b1,
//     plus atomic partial sums for dice-1 batch stats.
// Layout: 256 threads = 8 groups of 32 lanes. group g -> (b_sub = g>>1,
// half = g&1). Lane k owns features (k, 32+k, 64+k). Each group processes
// history items l = 2*i + half; the ub row is gathered coalesced once and
// used for BOTH score (5-step shuffle reduce) and browse accumulation.
// ---------------------------------------------------------------------------
__global__ __launch_bounds__(256) void k_fused1(
    const int* __restrict__ user, const int* __restrict__ item,
    const int* __restrict__ rec,
    const float* __restrict__ tu, const float* __restrict__ t1,
    const float* __restrict__ t2, const float* __restrict__ t3,
    const float* __restrict__ w_att1, const float* __restrict__ b_att1,
    const float* __restrict__ w_att2, const float* __restrict__ b_att2,
    const float* __restrict__ w1, const float* __restrict__ b1,
    float* __restrict__ y1, float* __restrict__ asum1, float* __restrict__ asq1)
{
    __shared__ float s_v[292];                 // 0..95 v1+v3 | 96..191 v2-v3 | 192..287 v4 | 288 const
    __shared__ int   s_idx[BPB * L * 3];
    __shared__ __align__(16) float s_feat[BPB][256];
    __shared__ float s_part[8][E];

    const int t  = threadIdx.x;
    const int b0 = blockIdx.x * BPB;
    const int g = t >> 5, lane = t & 31;
    const int bs = g >> 1, half = g & 1;

    // ---- collapse the linear attention MLP (w_att2 @ w_att1) -------------
    for (int j = t; j < 289; j += 256) {
        float s = 0.f;
        if (j < 96) {
            #pragma unroll
            for (int k = 0; k < NA; ++k)
                s += w_att2[k] * (w_att1[k * 384 + j] + w_att1[k * 384 + 192 + j]);
        } else if (j < 192) {
            int e = j - 96;
            #pragma unroll
            for (int k = 0; k < NA; ++k)
                s += w_att2[k] * (w_att1[k * 384 + 96 + e] - w_att1[k * 384 + 192 + e]);
        } else if (j < 288) {
            int e = j - 192;
            #pragma unroll
            for (int k = 0; k < NA; ++k)
                s += w_att2[k] * w_att1[k * 384 + 288 + e];
        } else {
            s = b_att2[0];
            #pragma unroll
            for (int k = 0; k < NA; ++k) s += w_att2[k] * b_att1[k];
        }
        s_v[j] = s;
    }

    // ---- stage history indices (coalesced) --------------------------------
    for (int i = t; i < BPB * L * 3; i += 256) s_idx[i] = rec[b0 * L * 3 + i];

    // ---- user embedding into feat[192..255] -------------------------------
    {
        int bu = t >> 6, u = t & 63;
        s_feat[bu][192 + u] = tu[(size_t)user[b0 + bu] * U + u];
    }

    // ---- q gathers (independent of LDS; issue early) ----------------------
    const float q0 = t1[item[(b0 + bs) * 3 + 0] * 32 + lane];
    const float q1 = t2[item[(b0 + bs) * 3 + 1] * 32 + lane];
    const float q2 = t3[item[(b0 + bs) * 3 + 2] * 32 + lane];

    __syncthreads();

    // per-row score weights w[e] = (v2-v3)[e] + q[e]*v4[e]; const cb
    const float wa = s_v[96 + lane]      + q0 * s_v[192 + lane];
    const float wb = s_v[96 + 32 + lane] + q1 * s_v[192 + 32 + lane];
    const float wc = s_v[96 + 64 + lane] + q2 * s_v[192 + 64 + lane];
    float cb = q0 * s_v[lane] + q1 * s_v[32 + lane] + q2 * s_v[64 + lane];
    #pragma unroll
    for (int m = 16; m > 0; m >>= 1) cb += __shfl_xor(cb, m);
    cb += s_v[288];

    if (half == 0) {        // item_emb into feat[0..95]
        s_feat[bs][lane]      = q0;
        s_feat[bs][32 + lane] = q1;
        s_feat[bs][64 + lane] = q2;
    }

    // ---- fused score + browse over this group's 100 history items ---------
    const int* myidx = s_idx + bs * L * 3;
    float a0 = 0.f, a1v = 0.f, a2v = 0.f;
    #pragma unroll 2
    for (int i = 0; i < L / 2; ++i) {
        const int l  = 2 * i + half;
        const int i0 = myidx[l * 3], i1 = myidx[l * 3 + 1], i2 = myidx[l * 3 + 2];
        const float u0 = t1[i0 * 32 + lane];
        const float u1 = t2[i1 * 32 + lane];
        const float u2 = t3[i2 * 32 + lane];
        float p = u0 * wa + u1 * wb + u2 * wc;
        #pragma unroll
        for (int m = 16; m > 0; m >>= 1) p += __shfl_xor(p, m);
        const float sc = (i0 == 0) ? 0.f : (cb + p);
        a0 += sc * u0; a1v += sc * u1; a2v += sc * u2;
    }
    s_part[g][lane]      = a0;
    s_part[g][32 + lane] = a1v;
    s_part[g][64 + lane] = a2v;
    __syncthreads();

    if (t < E) {            // browse into feat[96..191]
        #pragma unroll
        for (int bb = 0; bb < BPB; ++bb)
            s_feat[bb][96 + t] = s_part[2 * bb][t] + s_part[2 * bb + 1][t];
    }
    __syncthreads();

    // ---- y1 = feat @ w1^T + b1 (thread j owns w1 row j, reused BPB x) -----
    if (t < H1) {
        const float4* wr = (const float4*)(w1 + t * 256);
        float acc[BPB];
        const float bj = b1[t];
        #pragma unroll
        for (int bb = 0; bb < BPB; ++bb) acc[bb] = bj;
        #pragma unroll 4
        for (int k = 0; k < 64; ++k) {
            const float4 w = wr[k];
            #pragma unroll
            for (int bb = 0; bb < BPB; ++bb) {
                const float4 f = ((const float4*)s_feat[bb])[k];
                acc[bb] += w.x * f.x + w.y * f.y + w.z * f.z + w.w * f.w;
            }
        }
        float s1 = 0.f, s2 = 0.f;
        #pragma unroll
        for (int bb = 0; bb < BPB; ++bb) {
            y1[(size_t)(b0 + bb) * H1 + t] = acc[bb];
            s1 += acc[bb]; s2 += acc[bb] * acc[bb];
        }
        atomicAdd(asum1 + t, s1);
        atomicAdd(asq1 + t, s2);
    }
}

// ---------------------------------------------------------------------------
// K2: dice(y1) -> y2 = x @ w2^T + b2, plus atomic stats for dice-2
// ---------------------------------------------------------------------------
__global__ __launch_bounds__(256) void k_mlp(
    const float* __restrict__ y1,
    const float* __restrict__ asum1, const float* __restrict__ asq1,
    const float* __restrict__ a1, const float* __restrict__ g1,
    const float* __restrict__ be1,
    const float* __restrict__ w2, const float* __restrict__ b2,
    float* __restrict__ y2, float* __restrict__ asum2, float* __restrict__ asq2)
{
    __shared__ float s_sc[H1], s_sh[H1], s_al[H1];
    __shared__ __align__(16) float s_x[MB][H1];
    const int t = threadIdx.x, b0 = blockIdx.x * MB;

    if (t < H1) {
        const float mean = asum1[t] * (1.f / B);
        float var = (asq1[t] - (float)B * mean * mean) * (1.f / (B - 1));
        var = fmaxf(var, 0.f);
        const float a = g1[t] * rsqrtf(var + 1e-8f);
        s_sc[t] = a; s_sh[t] = be1[t] - mean * a; s_al[t] = a1[t];
    }
    __syncthreads();
    if (t < H1) {
        #pragma unroll
        for (int bb = 0; bb < MB; ++bb) {
            const float xn = y1[(size_t)(b0 + bb) * H1 + t] * s_sc[t] + s_sh[t];
            const float p  = sigf(xn);
            s_x[bb][t] = xn * (p + s_al[t] * (1.f - p));
        }
    }
    __syncthreads();
    if (t < H2) {
        const float4* wr = (const float4*)(w2 + t * H1);
        float acc[MB];
        const float bj = b2[t];
        #pragma unroll
        for (int bb = 0; bb < MB; ++bb) acc[bb] = bj;
        #pragma unroll 2
        for (int k = 0; k < H1 / 4; ++k) {
            const float4 w = wr[k];
            #pragma unroll
            for (int bb = 0; bb < MB; ++bb) {
                const float4 x = ((const float4*)s_x[bb])[k];
                acc[bb] += w.x * x.x + w.y * x.y + w.z * x.z + w.w * x.w;
            }
        }
        float s1 = 0.f, s2 = 0.f;
        #pragma unroll
        for (int bb = 0; bb < MB; ++bb) {
            y2[(size_t)(b0 + bb) * H2 + t] = acc[bb];
            s1 += acc[bb]; s2 += acc[bb] * acc[bb];
        }
        atomicAdd(asum2 + t, s1);
        atomicAdd(asq2 + t, s2);
    }
}

// ---------------------------------------------------------------------------
// K3: dice(y2), dot with w3, sigmoid. NB batch rows per block, LDS-staged.
// ---------------------------------------------------------------------------
__global__ __launch_bounds__(256) void k_final(
    const float* __restrict__ y2,
    const float* __restrict__ asum2, const float* __restrict__ asq2,
    const float* __restrict__ a2, const float* __restrict__ g2,
    const float* __restrict__ be2,
    const float* __restrict__ w3, const float* __restrict__ b3,
    float* __restrict__ out)
{
    __shared__ float s_sc[H2], s_sh[H2], s_al[H2], s_w3[H2];
    __shared__ float s_y[NB * H2];
    const int t = threadIdx.x, b0 = blockIdx.x * NB;

    if (t < H2) {
        const float mean = asum2[t] * (1.f / B);
        float var = (asq2[t] - (float)B * mean * mean) * (1.f / (B - 1));
        var = fmaxf(var, 0.f);
        const float a = g2[t] * rsqrtf(var + 1e-8f);
        s_sc[t] = a; s_sh[t] = be2[t] - mean * a;
        s_al[t] = a2[t]; s_w3[t] = w3[t];
    }
    for (int i = t; i < NB * H2; i += 256) s_y[i] = y2[(size_t)b0 * H2 + i];
    __syncthreads();

    if (t < NB) {
        float acc = b3[0];
        #pragma unroll 4
        for (int j = 0; j < H2; ++j) {
            const float xn = s_y[t * H2 + j] * s_sc[j] + s_sh[j];
            const float p  = sigf(xn);
            acc += xn * (p + s_al[j] * (1.f - p)) * s_w3[j];
        }
        out[b0 + t] = sigf(acc);
    }
}

} // namespace

extern "C" void kernel_launch(void* const* d_in, const int* in_sizes, int n_in,
                              void* d_out, int out_size, void* d_ws, size_t ws_size,
                              hipStream_t stream) {
    const int*   user   = (const int*)d_in[0];
    const int*   item   = (const int*)d_in[1];
    const int*   rec    = (const int*)d_in[2];
    const float* tu     = (const float*)d_in[3];
    const float* t1     = (const float*)d_in[4];
    const float* t2     = (const float*)d_in[5];
    const float* t3     = (const float*)d_in[6];
    const float* w_att1 = (const float*)d_in[7];
    const float* b_att1 = (const float*)d_in[8];
    const float* w_att2 = (const float*)d_in[9];
    const float* b_att2 = (const float*)d_in[10];
    const float* w1     = (const float*)d_in[11];
    const float* b1     = (const float*)d_in[12];
    const float* a1     = (const float*)d_in[13];
    const float* g1     = (const float*)d_in[14];
    const float* be1    = (const float*)d_in[15];
    const float* w2     = (const float*)d_in[16];
    const float* b2     = (const float*)d_in[17];
    const float* a2     = (const float*)d_in[18];
    const float* g2     = (const float*)d_in[19];
    const float* be2    = (const float*)d_in[20];
    const float* w3     = (const float*)d_in[21];
    const float* b3     = (const float*)d_in[22];
    float* out = (float*)d_out;

    float* ws    = (float*)d_ws;
    float* asum1 = ws;            // 200 (pad to 256)
    float* asq1  = ws + 256;      // 200
    float* asum2 = ws + 512;      // 80
    float* asq2  = ws + 640;      // 80
    float* y1    = ws + 768;      // B*H1
    float* y2    = y1 + B * H1;   // B*H2

    hipMemsetAsync(ws, 0, 768 * sizeof(float), stream);

    hipLaunchKernelGGL(k_fused1, dim3(B / BPB), dim3(256), 0, stream,
                       user, item, rec, tu, t1, t2, t3,
                       w_att1, b_att1, w_att2, b_att2, w1, b1,
                       y1, asum1, asq1);
    hipLaunchKernelGGL(k_mlp, dim3(B / MB), dim3(256), 0, stream,
                       y1, asum1, asq1, a1, g1, be1, w2, b2,
                       y2, asum2, asq2);
    hipLaunchKernelGGL(k_final, dim3(B / NB), dim3(256), 0, stream,
                       y2, asum2, asq2, a2, g2, be2, w3, b3, out);
}

// Round 3
// 76.966 us; speedup vs baseline: 1.5835x; 1.2308x over previous
//
#include <hip/hip_runtime.h>
#include <math.h>

namespace {

constexpr int B   = 2048;
constexpr int L   = 200;
constexpr int E   = 96;    // 3 * D_FEAT
constexpr int U   = 64;
constexpr int NA  = 36;    // HID_ATT
constexpr int H1  = 200;
constexpr int H2  = 80;
constexpr int R1  = 8;     // rows per block, y1 GEMM
constexpr int R2  = 8;     // rows per block, y2 GEMM
constexpr int R3  = 8;     // rows per block, final

__device__ __forceinline__ float sigf(float x) {
    return 1.0f / (1.0f + __expf(-x));
}

// ---------------------------------------------------------------------------
// K0: collapse the linear attention MLP (w_att2 @ w_att1), once.
// vbuf[0..95] = v1+v3 (mult q) | [96..191] = v2-v3 (mult ub) |
// [192..287] = v4 (mult q*ub)  | [288] = w_att2·b_att1 + b_att2
// ---------------------------------------------------------------------------
__global__ void k_pre(const float* __restrict__ w_att1,
                      const float* __restrict__ b_att1,
                      const float* __restrict__ w_att2,
                      const float* __restrict__ b_att2,
                      float* __restrict__ vbuf) {
    int j = threadIdx.x;               // 384 threads, use 289
    if (j < 96) {
        float s = 0.f;
        #pragma unroll
        for (int k = 0; k < NA; ++k)
            s += w_att2[k] * (w_att1[k * 384 + j] + w_att1[k * 384 + 192 + j]);
        vbuf[j] = s;
    } else if (j < 192) {
        int e = j - 96; float s = 0.f;
        #pragma unroll
        for (int k = 0; k < NA; ++k)
            s += w_att2[k] * (w_att1[k * 384 + 96 + e] - w_att1[k * 384 + 192 + e]);
        vbuf[j] = s;
    } else if (j < 288) {
        int e = j - 192; float s = 0.f;
        #pragma unroll
        for (int k = 0; k < NA; ++k)
            s += w_att2[k] * w_att1[k * 384 + 288 + e];
        vbuf[j] = s;
    } else if (j == 288) {
        float c = b_att2[0];
        #pragma unroll
        for (int k = 0; k < NA; ++k) c += w_att2[k] * b_att1[k];
        vbuf[288] = c;
    }
}

// ---------------------------------------------------------------------------
// K1: one batch row per block; 8 groups x 32 lanes, 25 history items each.
// Fused score + browse; outputs feat[256] row to global.
// ---------------------------------------------------------------------------
__global__ __launch_bounds__(256) void k_attn(
    const int* __restrict__ user, const int* __restrict__ item,
    const int* __restrict__ rec,
    const float* __restrict__ tu, const float* __restrict__ t1,
    const float* __restrict__ t2, const float* __restrict__ t3,
    const float* __restrict__ vbuf, float* __restrict__ feat)
{
    __shared__ float s_v[292];
    __shared__ float s_w[E];
    __shared__ __align__(16) float s_feat[256];
    __shared__ float s_part[8][E];
    __shared__ int   s_idx[L * 3];

    const int b = blockIdx.x, t = threadIdx.x;
    const int g = t >> 5, lane = t & 31;

    for (int i = t; i < L * 3; i += 256) s_idx[i] = rec[b * L * 3 + i];
    for (int i = t; i < 289; i += 256) s_v[i] = vbuf[i];
    if (t < E) {                         // q = item_emb -> feat[0..95]
        int f = t >> 5, e = t & 31;
        const float* tab = (f == 0) ? t1 : ((f == 1) ? t2 : t3);
        s_feat[t] = tab[item[b * 3 + f] * 32 + e];
    }
    if (t >= 192) s_feat[t] = tu[(size_t)user[b] * U + (t - 192)];  // user emb
    __syncthreads();

    if (t < E) s_w[t] = s_v[96 + t] + s_feat[t] * s_v[192 + t];
    __syncthreads();

    const float wa = s_w[lane], wb = s_w[32 + lane], wc = s_w[64 + lane];
    float cb = s_feat[lane] * s_v[lane] + s_feat[32 + lane] * s_v[32 + lane]
             + s_feat[64 + lane] * s_v[64 + lane];
    #pragma unroll
    for (int m = 16; m > 0; m >>= 1) cb += __shfl_xor(cb, m);
    cb += s_v[288];

    const int* myidx = s_idx + g * 25 * 3;
    float a0 = 0.f, a1v = 0.f, a2v = 0.f;
    #pragma unroll 5
    for (int i = 0; i < 25; ++i) {
        const int i0 = myidx[i * 3], i1 = myidx[i * 3 + 1], i2 = myidx[i * 3 + 2];
        const float u0 = t1[i0 * 32 + lane];
        const float u1 = t2[i1 * 32 + lane];
        const float u2 = t3[i2 * 32 + lane];
        float p = u0 * wa + u1 * wb + u2 * wc;
        #pragma unroll
        for (int m = 16; m > 0; m >>= 1) p += __shfl_xor(p, m);
        const float sc = (i0 == 0) ? 0.f : (cb + p);
        a0 += sc * u0; a1v += sc * u1; a2v += sc * u2;
    }
    s_part[g][lane]      = a0;
    s_part[g][32 + lane] = a1v;
    s_part[g][64 + lane] = a2v;
    __syncthreads();

    if (t < E) {                         // browse -> feat[96..191]
        float s = 0.f;
        #pragma unroll
        for (int gg = 0; gg < 8; ++gg) s += s_part[gg][t];
        s_feat[96 + t] = s;
    }
    __syncthreads();

    feat[(size_t)b * 256 + t] = s_feat[t];
}

// ---------------------------------------------------------------------------
// K2: y1 = feat @ w1^T + b1 over R1-row tiles; per-block stats atomics.
// ---------------------------------------------------------------------------
__global__ __launch_bounds__(256) void k_gemm1(
    const float* __restrict__ feat,
    const float* __restrict__ w1, const float* __restrict__ b1,
    float* __restrict__ y1, float* __restrict__ asum1, float* __restrict__ asq1)
{
    __shared__ __align__(16) float s_f[R1 * 256];
    const int t = threadIdx.x, b0 = blockIdx.x * R1;

    const float4* src = (const float4*)(feat + (size_t)b0 * 256);
    float4* dst = (float4*)s_f;
    #pragma unroll
    for (int i = 0; i < R1 * 64 / 256; ++i) dst[t + i * 256] = src[t + i * 256];
    __syncthreads();

    if (t < H1) {
        const float4* wr = (const float4*)(w1 + t * 256);
        float acc[R1];
        const float bj = b1[t];
        #pragma unroll
        for (int bb = 0; bb < R1; ++bb) acc[bb] = bj;
        #pragma unroll 4
        for (int k = 0; k < 64; ++k) {
            const float4 w = wr[k];
            #pragma unroll
            for (int bb = 0; bb < R1; ++bb) {
                const float4 f = ((const float4*)(s_f + bb * 256))[k];
                acc[bb] += w.x * f.x + w.y * f.y + w.z * f.z + w.w * f.w;
            }
        }
        float s1 = 0.f, s2 = 0.f;
        #pragma unroll
        for (int bb = 0; bb < R1; ++bb) {
            y1[(size_t)(b0 + bb) * H1 + t] = acc[bb];
            s1 += acc[bb]; s2 += acc[bb] * acc[bb];
        }
        atomicAdd(asum1 + t, s1);
        atomicAdd(asq1 + t, s2);
    }
}

// ---------------------------------------------------------------------------
// K3: dice(y1) -> y2 = x @ w2^T + b2 over R2-row tiles; stats-2 atomics.
// 240 active threads: col j = t%80, row-group rg = t/80 (rows 3/3/2).
// ---------------------------------------------------------------------------
__global__ __launch_bounds__(256) void k_mlp(
    const float* __restrict__ y1,
    const float* __restrict__ asum1, const float* __restrict__ asq1,
    const float* __restrict__ a1, const float* __restrict__ g1,
    const float* __restrict__ be1,
    const float* __restrict__ w2, const float* __restrict__ b2,
    float* __restrict__ y2, float* __restrict__ asum2, float* __restrict__ asq2)
{
    __shared__ float s_sc[H1], s_sh[H1], s_al[H1];
    __shared__ __align__(16) float s_x[R2][H1];
    __shared__ float s_p1[3][H2], s_p2[3][H2];
    const int t = threadIdx.x, b0 = blockIdx.x * R2;

    if (t < H1) {
        const float mean = asum1[t] * (1.f / B);
        float var = (asq1[t] - (float)B * mean * mean) * (1.f / (B - 1));
        var = fmaxf(var, 0.f);
        const float a = g1[t] * rsqrtf(var + 1e-8f);
        s_sc[t] = a; s_sh[t] = be1[t] - mean * a; s_al[t] = a1[t];
    }
    __syncthreads();

    for (int i = t; i < R2 * H1; i += 256) {
        const int bb = i / H1, j = i - bb * H1;
        const float xn = y1[(size_t)b0 * H1 + i] * s_sc[j] + s_sh[j];
        const float p  = sigf(xn);
        s_x[bb][j] = xn * (p + s_al[j] * (1.f - p));
    }
    __syncthreads();

    const int j = t % H2, rg = t / H2;       // rg in 0..2 for t<240
    if (t < 240) {
        const int base = rg * 3;
        const int nb = (rg < 2) ? 3 : 2;
        const float4* wr = (const float4*)(w2 + j * H1);
        float acc[3];
        const float bj = b2[j];
        #pragma unroll
        for (int r = 0; r < 3; ++r) acc[r] = bj;
        #pragma unroll 2
        for (int k = 0; k < H1 / 4; ++k) {
            const float4 w = wr[k];
            for (int r = 0; r < nb; ++r) {
                const float4 x = ((const float4*)s_x[base + r])[k];
                acc[r] += w.x * x.x + w.y * x.y + w.z * x.z + w.w * x.w;
            }
        }
        float s1 = 0.f, s2 = 0.f;
        for (int r = 0; r < nb; ++r) {
            y2[(size_t)(b0 + base + r) * H2 + j] = acc[r];
            s1 += acc[r]; s2 += acc[r] * acc[r];
        }
        s_p1[rg][j] = s1; s_p2[rg][j] = s2;
    }
    __syncthreads();
    if (t < H2) {
        atomicAdd(asum2 + t, s_p1[0][t] + s_p1[1][t] + s_p1[2][t]);
        atomicAdd(asq2 + t, s_p2[0][t] + s_p2[1][t] + s_p2[2][t]);
    }
}

// ---------------------------------------------------------------------------
// K4: dice(y2), dot w3, sigmoid. 8 rows/block, 32 lanes per row.
// ---------------------------------------------------------------------------
__global__ __launch_bounds__(256) void k_final(
    const float* __restrict__ y2,
    const float* __restrict__ asum2, const float* __restrict__ asq2,
    const float* __restrict__ a2, const float* __restrict__ g2,
    const float* __restrict__ be2,
    const float* __restrict__ w3, const float* __restrict__ b3,
    float* __restrict__ out)
{
    __shared__ float s_c[H2], s_s[H2], s_aw[H2];
    const int t = threadIdx.x, b0 = blockIdx.x * R3;
    const int g = t >> 5, lane = t & 31;

    if (t < H2) {
        const float mean = asum2[t] * (1.f / B);
        float var = (asq2[t] - (float)B * mean * mean) * (1.f / (B - 1));
        var = fmaxf(var, 0.f);
        const float a = g2[t] * rsqrtf(var + 1e-8f);
        s_c[t] = a; s_s[t] = be2[t] - mean * a; s_aw[t] = a2[t];
    }
    __syncthreads();

    const int r = b0 + g;
    float acc = 0.f;
    #pragma unroll
    for (int jj = 0; jj < 3; ++jj) {
        const int j = lane + jj * 32;
        if (j < H2) {
            const float xn = y2[(size_t)r * H2 + j] * s_c[j] + s_s[j];
            const float p  = sigf(xn);
            acc += xn * (p + s_aw[j] * (1.f - p)) * w3[j];
        }
    }
    #pragma unroll
    for (int m = 16; m > 0; m >>= 1) acc += __shfl_xor(acc, m);
    if (lane == 0) out[r] = sigf(acc + b3[0]);
}

} // namespace

extern "C" void kernel_launch(void* const* d_in, const int* in_sizes, int n_in,
                              void* d_out, int out_size, void* d_ws, size_t ws_size,
                              hipStream_t stream) {
    const int*   user   = (const int*)d_in[0];
    const int*   item   = (const int*)d_in[1];
    const int*   rec    = (const int*)d_in[2];
    const float* tu     = (const float*)d_in[3];
    const float* t1     = (const float*)d_in[4];
    const float* t2     = (const float*)d_in[5];
    const float* t3     = (const float*)d_in[6];
    const float* w_att1 = (const float*)d_in[7];
    const float* b_att1 = (const float*)d_in[8];
    const float* w_att2 = (const float*)d_in[9];
    const float* b_att2 = (const float*)d_in[10];
    const float* w1     = (const float*)d_in[11];
    const float* b1     = (const float*)d_in[12];
    const float* a1     = (const float*)d_in[13];
    const float* g1     = (const float*)d_in[14];
    const float* be1    = (const float*)d_in[15];
    const float* w2     = (const float*)d_in[16];
    const float* b2     = (const float*)d_in[17];
    const float* a2     = (const float*)d_in[18];
    const float* g2     = (const float*)d_in[19];
    const float* be2    = (const float*)d_in[20];
    const float* w3     = (const float*)d_in[21];
    const float* b3     = (const float*)d_in[22];
    float* out = (float*)d_out;

    float* ws    = (float*)d_ws;
    float* asum1 = ws;                      // [0,256)
    float* asq1  = ws + 256;                // [256,512)
    float* asum2 = ws + 512;                // [512,640)
    float* asq2  = ws + 640;                // [640,768)
    float* vbuf  = ws + 768;                // [768,1088)
    float* feat  = ws + 1088;               // B*256
    float* y1    = feat + (size_t)B * 256;  // B*H1
    float* y2    = y1 + (size_t)B * H1;     // B*H2

    hipMemsetAsync(ws, 0, 768 * sizeof(float), stream);

    hipLaunchKernelGGL(k_pre,   dim3(1),      dim3(384), 0, stream,
                       w_att1, b_att1, w_att2, b_att2, vbuf);
    hipLaunchKernelGGL(k_attn,  dim3(B),      dim3(256), 0, stream,
                       user, item, rec, tu, t1, t2, t3, vbuf, feat);
    hipLaunchKernelGGL(k_gemm1, dim3(B / R1), dim3(256), 0, stream,
                       feat, w1, b1, y1, asum1, asq1);
    hipLaunchKernelGGL(k_mlp,   dim3(B / R2), dim3(256), 0, stream,
                       y1, asum1, asq1, a1, g1, be1, w2, b2, y2, asum2, asq2);
    hipLaunchKernelGGL(k_final, dim3(B / R3), dim3(256), 0, stream,
                       y2, asum2, asq2, a2, g2, be2, w3, b3, out);
}

// Round 4
// 74.386 us; speedup vs baseline: 1.6384x; 1.0347x over previous
//
#include <hip/hip_runtime.h>
#include <math.h>

namespace {

constexpr int B   = 2048;
constexpr int L   = 200;
constexpr int E   = 96;    // 3 * D_FEAT
constexpr int U   = 64;
constexpr int NA  = 36;    // HID_ATT
constexpr int H1  = 200;
constexpr int H2  = 80;
constexpr int R1  = 8;     // rows per block, y1 GEMM
constexpr int R2  = 8;     // rows per block, y2 GEMM
constexpr int R3  = 8;     // rows per block, final

__device__ __forceinline__ float sigf(float x) {
    return 1.0f / (1.0f + __expf(-x));
}

// ---------------------------------------------------------------------------
// K0: zero the stats accumulators (replaces a 41us runtime fillBuffer!) and
// collapse the linear attention MLP (w_att2 @ w_att1), once.
// vbuf[0..95] = v1+v3 (mult q) | [96..191] = v2-v3 (mult ub) |
// [192..287] = v4 (mult q*ub)  | [288] = w_att2·b_att1 + b_att2
// ---------------------------------------------------------------------------
__global__ void k_pre(const float* __restrict__ w_att1,
                      const float* __restrict__ b_att1,
                      const float* __restrict__ w_att2,
                      const float* __restrict__ b_att2,
                      float* __restrict__ stats,   // 768 floats to zero
                      float* __restrict__ vbuf) {
    int j = threadIdx.x;               // 384 threads
    stats[j] = 0.f;
    stats[j + 384] = 0.f;
    if (j < 96) {
        float s = 0.f;
        #pragma unroll
        for (int k = 0; k < NA; ++k)
            s += w_att2[k] * (w_att1[k * 384 + j] + w_att1[k * 384 + 192 + j]);
        vbuf[j] = s;
    } else if (j < 192) {
        int e = j - 96; float s = 0.f;
        #pragma unroll
        for (int k = 0; k < NA; ++k)
            s += w_att2[k] * (w_att1[k * 384 + 96 + e] - w_att1[k * 384 + 192 + e]);
        vbuf[j] = s;
    } else if (j < 288) {
        int e = j - 192; float s = 0.f;
        #pragma unroll
        for (int k = 0; k < NA; ++k)
            s += w_att2[k] * w_att1[k * 384 + 288 + e];
        vbuf[j] = s;
    } else if (j == 288) {
        float c = b_att2[0];
        #pragma unroll
        for (int k = 0; k < NA; ++k) c += w_att2[k] * b_att1[k];
        vbuf[288] = c;
    }
}

// ---------------------------------------------------------------------------
// K1: one batch row per block; 8 groups x 32 lanes, 25 history items each.
// Fused score + browse; outputs feat[256] row to global.
// ---------------------------------------------------------------------------
__global__ __launch_bounds__(256) void k_attn(
    const int* __restrict__ user, const int* __restrict__ item,
    const int* __restrict__ rec,
    const float* __restrict__ tu, const float* __restrict__ t1,
    const float* __restrict__ t2, const float* __restrict__ t3,
    const float* __restrict__ vbuf, float* __restrict__ feat)
{
    __shared__ float s_v[292];
    __shared__ float s_w[E];
    __shared__ __align__(16) float s_feat[256];
    __shared__ float s_part[8][E];
    __shared__ int   s_idx[L * 3];

    const int b = blockIdx.x, t = threadIdx.x;
    const int g = t >> 5, lane = t & 31;

    for (int i = t; i < L * 3; i += 256) s_idx[i] = rec[b * L * 3 + i];
    for (int i = t; i < 289; i += 256) s_v[i] = vbuf[i];
    if (t < E) {                         // q = item_emb -> feat[0..95]
        int f = t >> 5, e = t & 31;
        const float* tab = (f == 0) ? t1 : ((f == 1) ? t2 : t3);
        s_feat[t] = tab[item[b * 3 + f] * 32 + e];
    }
    if (t >= 192) s_feat[t] = tu[(size_t)user[b] * U + (t - 192)];  // user emb
    __syncthreads();

    if (t < E) s_w[t] = s_v[96 + t] + s_feat[t] * s_v[192 + t];
    __syncthreads();

    const float wa = s_w[lane], wb = s_w[32 + lane], wc = s_w[64 + lane];
    float cb = s_feat[lane] * s_v[lane] + s_feat[32 + lane] * s_v[32 + lane]
             + s_feat[64 + lane] * s_v[64 + lane];
    #pragma unroll
    for (int m = 16; m > 0; m >>= 1) cb += __shfl_xor(cb, m);
    cb += s_v[288];

    const int* myidx = s_idx + g * 25 * 3;
    float a0 = 0.f, a1v = 0.f, a2v = 0.f;
    #pragma unroll 5
    for (int i = 0; i < 25; ++i) {
        const int i0 = myidx[i * 3], i1 = myidx[i * 3 + 1], i2 = myidx[i * 3 + 2];
        const float u0 = t1[i0 * 32 + lane];
        const float u1 = t2[i1 * 32 + lane];
        const float u2 = t3[i2 * 32 + lane];
        float p = u0 * wa + u1 * wb + u2 * wc;
        #pragma unroll
        for (int m = 16; m > 0; m >>= 1) p += __shfl_xor(p, m);
        const float sc = (i0 == 0) ? 0.f : (cb + p);
        a0 += sc * u0; a1v += sc * u1; a2v += sc * u2;
    }
    s_part[g][lane]      = a0;
    s_part[g][32 + lane] = a1v;
    s_part[g][64 + lane] = a2v;
    __syncthreads();

    if (t < E) {                         // browse -> feat[96..191]
        float s = 0.f;
        #pragma unroll
        for (int gg = 0; gg < 8; ++gg) s += s_part[gg][t];
        s_feat[96 + t] = s;
    }
    __syncthreads();

    feat[(size_t)b * 256 + t] = s_feat[t];
}

// ---------------------------------------------------------------------------
// K2: y1 = feat @ w1^T + b1 over R1-row tiles; per-block stats atomics.
// ---------------------------------------------------------------------------
__global__ __launch_bounds__(256) void k_gemm1(
    const float* __restrict__ feat,
    const float* __restrict__ w1, const float* __restrict__ b1,
    float* __restrict__ y1, float* __restrict__ asum1, float* __restrict__ asq1)
{
    __shared__ __align__(16) float s_f[R1 * 256];
    const int t = threadIdx.x, b0 = blockIdx.x * R1;

    const float4* src = (const float4*)(feat + (size_t)b0 * 256);
    float4* dst = (float4*)s_f;
    #pragma unroll
    for (int i = 0; i < R1 * 64 / 256; ++i) dst[t + i * 256] = src[t + i * 256];
    __syncthreads();

    if (t < H1) {
        const float4* wr = (const float4*)(w1 + t * 256);
        float acc[R1];
        const float bj = b1[t];
        #pragma unroll
        for (int bb = 0; bb < R1; ++bb) acc[bb] = bj;
        #pragma unroll 4
        for (int k = 0; k < 64; ++k) {
            const float4 w = wr[k];
            #pragma unroll
            for (int bb = 0; bb < R1; ++bb) {
                const float4 f = ((const float4*)(s_f + bb * 256))[k];
                acc[bb] += w.x * f.x + w.y * f.y + w.z * f.z + w.w * f.w;
            }
        }
        float s1 = 0.f, s2 = 0.f;
        #pragma unroll
        for (int bb = 0; bb < R1; ++bb) {
            y1[(size_t)(b0 + bb) * H1 + t] = acc[bb];
            s1 += acc[bb]; s2 += acc[bb] * acc[bb];
        }
        atomicAdd(asum1 + t, s1);
        atomicAdd(asq1 + t, s2);
    }
}

// ---------------------------------------------------------------------------
// K3: dice(y1) -> y2 = x @ w2^T + b2 over R2-row tiles; stats-2 atomics.
// 240 active threads: col j = t%80, row-group rg = t/80 (rows 3/3/2).
// ---------------------------------------------------------------------------
__global__ __launch_bounds__(256) void k_mlp(
    const float* __restrict__ y1,
    const float* __restrict__ asum1, const float* __restrict__ asq1,
    const float* __restrict__ a1, const float* __restrict__ g1,
    const float* __restrict__ be1,
    const float* __restrict__ w2, const float* __restrict__ b2,
    float* __restrict__ y2, float* __restrict__ asum2, float* __restrict__ asq2)
{
    __shared__ float s_sc[H1], s_sh[H1], s_al[H1];
    __shared__ __align__(16) float s_x[R2][H1];
    __shared__ float s_p1[3][H2], s_p2[3][H2];
    const int t = threadIdx.x, b0 = blockIdx.x * R2;

    if (t < H1) {
        const float mean = asum1[t] * (1.f / B);
        float var = (asq1[t] - (float)B * mean * mean) * (1.f / (B - 1));
        var = fmaxf(var, 0.f);
        const float a = g1[t] * rsqrtf(var + 1e-8f);
        s_sc[t] = a; s_sh[t] = be1[t] - mean * a; s_al[t] = a1[t];
    }
    __syncthreads();

    for (int i = t; i < R2 * H1; i += 256) {
        const int bb = i / H1, j = i - bb * H1;
        const float xn = y1[(size_t)b0 * H1 + i] * s_sc[j] + s_sh[j];
        const float p  = sigf(xn);
        s_x[bb][j] = xn * (p + s_al[j] * (1.f - p));
    }
    __syncthreads();

    const int j = t % H2, rg = t / H2;       // rg in 0..2 for t<240
    if (t < 240) {
        const int base = rg * 3;
        const int nb = (rg < 2) ? 3 : 2;
        const float4* wr = (const float4*)(w2 + j * H1);
        float acc[3];
        const float bj = b2[j];
        #pragma unroll
        for (int r = 0; r < 3; ++r) acc[r] = bj;
        #pragma unroll 2
        for (int k = 0; k < H1 / 4; ++k) {
            const float4 w = wr[k];
            for (int r = 0; r < nb; ++r) {
                const float4 x = ((const float4*)s_x[base + r])[k];
                acc[r] += w.x * x.x + w.y * x.y + w.z * x.z + w.w * x.w;
            }
        }
        float s1 = 0.f, s2 = 0.f;
        for (int r = 0; r < nb; ++r) {
            y2[(size_t)(b0 + base + r) * H2 + j] = acc[r];
            s1 += acc[r]; s2 += acc[r] * acc[r];
        }
        s_p1[rg][j] = s1; s_p2[rg][j] = s2;
    }
    __syncthreads();
    if (t < H2) {
        atomicAdd(asum2 + t, s_p1[0][t] + s_p1[1][t] + s_p1[2][t]);
        atomicAdd(asq2 + t, s_p2[0][t] + s_p2[1][t] + s_p2[2][t]);
    }
}

// ---------------------------------------------------------------------------
// K4: dice(y2), dot w3, sigmoid. 8 rows/block, 32 lanes per row.
// ---------------------------------------------------------------------------
__global__ __launch_bounds__(256) void k_final(
    const float* __restrict__ y2,
    const float* __restrict__ asum2, const float* __restrict__ asq2,
    const float* __restrict__ a2, const float* __restrict__ g2,
    const float* __restrict__ be2,
    const float* __restrict__ w3, const float* __restrict__ b3,
    float* __restrict__ out)
{
    __shared__ float s_c[H2], s_s[H2], s_aw[H2];
    const int t = threadIdx.x, b0 = blockIdx.x * R3;
    const int g = t >> 5, lane = t & 31;

    if (t < H2) {
        const float mean = asum2[t] * (1.f / B);
        float var = (asq2[t] - (float)B * mean * mean) * (1.f / (B - 1));
        var = fmaxf(var, 0.f);
        const float a = g2[t] * rsqrtf(var + 1e-8f);
        s_c[t] = a; s_s[t] = be2[t] - mean * a; s_aw[t] = a2[t];
    }
    __syncthreads();

    const int r = b0 + g;
    float acc = 0.f;
    #pragma unroll
    for (int jj = 0; jj < 3; ++jj) {
        const int j = lane + jj * 32;
        if (j < H2) {
            const float xn = y2[(size_t)r * H2 + j] * s_c[j] + s_s[j];
            const float p  = sigf(xn);
            acc += xn * (p + s_aw[j] * (1.f - p)) * w3[j];
        }
    }
    #pragma unroll
    for (int m = 16; m > 0; m >>= 1) acc += __shfl_xor(acc, m);
    if (lane == 0) out[r] = sigf(acc + b3[0]);
}

} // namespace

extern "C" void kernel_launch(void* const* d_in, const int* in_sizes, int n_in,
                              void* d_out, int out_size, void* d_ws, size_t ws_size,
                              hipStream_t stream) {
    const int*   user   = (const int*)d_in[0];
    const int*   item   = (const int*)d_in[1];
    const int*   rec    = (const int*)d_in[2];
    const float* tu     = (const float*)d_in[3];
    const float* t1     = (const float*)d_in[4];
    const float* t2     = (const float*)d_in[5];
    const float* t3     = (const float*)d_in[6];
    const float* w_att1 = (const float*)d_in[7];
    const float* b_att1 = (const float*)d_in[8];
    const float* w_att2 = (const float*)d_in[9];
    const float* b_att2 = (const float*)d_in[10];
    const float* w1     = (const float*)d_in[11];
    const float* b1     = (const float*)d_in[12];
    const float* a1     = (const float*)d_in[13];
    const float* g1     = (const float*)d_in[14];
    const float* be1    = (const float*)d_in[15];
    const float* w2     = (const float*)d_in[16];
    const float* b2     = (const float*)d_in[17];
    const float* a2     = (const float*)d_in[18];
    const float* g2     = (const float*)d_in[19];
    const float* be2    = (const float*)d_in[20];
    const float* w3     = (const float*)d_in[21];
    const float* b3     = (const float*)d_in[22];
    float* out = (float*)d_out;

    float* ws    = (float*)d_ws;
    float* asum1 = ws;                      // [0,256)
    float* asq1  = ws + 256;                // [256,512)
    float* asum2 = ws + 512;                // [512,640)
    float* asq2  = ws + 640;                // [640,768)
    float* vbuf  = ws + 768;                // [768,1088)
    float* feat  = ws + 1088;               // B*256
    float* y1    = feat + (size_t)B * 256;  // B*H1
    float* y2    = y1 + (size_t)B * H1;     // B*H2

    hipLaunchKernelGGL(k_pre,   dim3(1),      dim3(384), 0, stream,
                       w_att1, b_att1, w_att2, b_att2, ws, vbuf);
    hipLaunchKernelGGL(k_attn,  dim3(B),      dim3(256), 0, stream,
                       user, item, rec, tu, t1, t2, t3, vbuf, feat);
    hipLaunchKernelGGL(k_gemm1, dim3(B / R1), dim3(256), 0, stream,
                       feat, w1, b1, y1, asum1, asq1);
    hipLaunchKernelGGL(k_mlp,   dim3(B / R2), dim3(256), 0, stream,
                       y1, asum1, asq1, a1, g1, be1, w2, b2, y2, asum2, asq2);
    hipLaunchKernelGGL(k_final, dim3(B / R3), dim3(256), 0, stream,
                       y2, asum2, asq2, a2, g2, be2, w3, b3, out);
}